// Round 5
// baseline (259.187 us; speedup 1.0000x reference)
//
#include <hip/hip_runtime.h>

typedef __bf16 bf16x8 __attribute__((ext_vector_type(8)));
typedef float f32x4 __attribute__((ext_vector_type(4)));

#define B_ 16
#define T_ 1024
#define D_ 512
#define S_ 12
#define C_ 11
static constexpr int P_TOTAL = 2148960;  // 176 * (12*1024 - 78)

__device__ __host__ inline constexpr int pred_base(int i) {
  return C_ * B_ * (T_ * i - (i * (i + 1)) / 2);
}

__device__ inline unsigned short f2bf(float f) {
  unsigned int u = __float_as_uint(f);
  u += 0x7FFF + ((u >> 16) & 1);   // round-to-nearest-even
  return (unsigned short)(u >> 16);
}

__device__ inline void gld16(const void* g, void* l) {
  __builtin_amdgcn_global_load_lds(
      (const __attribute__((address_space(1))) void*)g,
      (__attribute__((address_space(3))) void*)l, 16, 0, 0);
}

// ---------------- prep: W [i][o][s] f32 -> wt [s][o][i] bf16 ----------------
__global__ __launch_bounds__(256) void prep_w(const float* __restrict__ W,
                                              unsigned short* __restrict__ wt) {
  __shared__ unsigned short tile[32][33][12];
  const int i0 = blockIdx.x * 32, o0 = blockIdx.y * 32;
#pragma unroll
  for (int q = 0; q < 48; ++q) {
    int idx = threadIdx.x + q * 256;
    int ii = idx / 384, rem = idx % 384;
    tile[ii][rem / 12][rem % 12] =
        f2bf(W[(size_t)(i0 + ii) * 6144 + (size_t)o0 * 12 + rem]);
  }
  __syncthreads();
#pragma unroll
  for (int q = 0; q < 48; ++q) {
    int idx = threadIdx.x + q * 256;
    int ss = idx / 1024, rem = idx % 1024;
    int oo = rem / 32, ii = rem % 32;
    wt[(size_t)ss * (D_ * D_) + (size_t)(o0 + oo) * D_ + (i0 + ii)] = tile[ii][oo][ss];
  }
}

// -- prep: transpose [b][D][T] f32 -> [b][T][D] bf16, both x and y (z=0..31) --
__global__ __launch_bounds__(256) void prep_t2(const float* __restrict__ xin,
                                               const float* __restrict__ yin,
                                               unsigned short* __restrict__ xo,
                                               unsigned short* __restrict__ yo) {
  __shared__ float tile[32][33];
  const int t0 = blockIdx.x * 32;
  const int d0 = blockIdx.y * 32;
  const int b = blockIdx.z & 15;
  const float* in = (blockIdx.z < 16) ? xin : yin;
  unsigned short* ob = (blockIdx.z < 16) ? xo : yo;
  const float* ib = in + (size_t)b * D_ * T_;
  const int r = threadIdx.x / 32, c = threadIdx.x % 32;
#pragma unroll
  for (int p = 0; p < 4; ++p) {
    int rr = r + p * 8;
    tile[rr][c] = ib[(size_t)(d0 + rr) * T_ + t0 + c];
  }
  __syncthreads();
  unsigned short* op = ob + (size_t)b * T_ * D_;
#pragma unroll
  for (int p = 0; p < 4; ++p) {
    int rr = r + p * 8;
    op[(size_t)(t0 + rr) * D_ + d0 + c] = f2bf(tile[c][rr]);
  }
}

// ---------------- labels ----------------
__global__ void labels_k(float* __restrict__ lab) {
  int k = blockIdx.x * 256 + threadIdx.x;
  if (k >= P_TOTAL) return;
  int i = 0;
#pragma unroll
  for (int q = 1; q < 12; ++q)
    if (k >= pred_base(q)) i = q;
  int rel = k - pred_base(i);
  int len = T_ - 1 - i;
  lab[k] = (rel < B_ * len) ? 1.0f : 0.0f;
}

// ---- GEMM: xp[bl][s][t][o] = xb[m][i] * wt[s][o][i] + bias[o] --------------
// 256 threads (4 waves, wave-tile 128x64), block tile 256m x 128n, BK=32,
// ring-3 LDS slots (72 KiB => 2 blocks/CU for cross-block de-phased overlap).
// One barrier + one counted vmcnt(6) per K-tile; all 12 frag ds_reads issued
// post-barrier in the shadow of the ms1 MFMA cluster. Persistent tiles with
// continuous staging; XCD-chunked tile order for A-panel L2 locality.
__global__ __launch_bounds__(256, 2) void gemm_xp(
    const unsigned short* __restrict__ xb,   // [bc*1024][512]
    const unsigned short* __restrict__ wt,   // [12][512 o][512 i]
    const float* __restrict__ bias,          // [512]
    unsigned short* __restrict__ xp,         // [bc][12][1024][512]
    int tiles, int chunk, int bpx) {
  __shared__ unsigned short lds[36864];      // 3 slots x 24KB (A 16KB + B 8KB)
  const int tid = threadIdx.x;
  const int w = tid >> 6, l = tid & 63;
  const int gm = w >> 1, gn = w & 1;         // wave tile: 128m x 64n
  const int fr = l & 15, sgrp = l >> 4;

  // staging source offsets (bytes): A 4 segs, B 2 segs; source pre-swizzled
  // (rule #21: LDS dest linear, inverse swizzle on global source).
  int soA[4], goA[4], soB[2], goB[2];
#pragma unroll
  for (int seg = 0; seg < 4; ++seg) {
    soA[seg] = tid * 16 + seg * 4096;
    int row = soA[seg] >> 6, sc = (soA[seg] >> 4) & 3;
    goA[seg] = row * 1024 + ((sc ^ ((row >> 1) & 3)) << 4);
  }
#pragma unroll
  for (int seg = 0; seg < 2; ++seg) {
    soB[seg] = tid * 16 + seg * 4096;
    int row = soB[seg] >> 6, sc = (soB[seg] >> 4) & 3;
    goB[seg] = row * 1024 + ((sc ^ ((row >> 1) & 3)) << 4);
  }

  auto stage = [&](const unsigned short* Akt, const unsigned short* Bkt, int slotB) {
#pragma unroll
    for (int seg = 0; seg < 4; ++seg)
      gld16((const char*)Akt + goA[seg], (char*)lds + slotB + soA[seg]);
#pragma unroll
    for (int seg = 0; seg < 2; ++seg)
      gld16((const char*)Bkt + goB[seg], (char*)lds + slotB + 16384 + soB[seg]);
  };

  // invariant swizzled frag byte-offsets within a slot
  int aOff[8], bOff[4];
#pragma unroll
  for (int fm = 0; fm < 8; ++fm) {
    int row = gm * 128 + fm * 16 + fr;
    aOff[fm] = row * 64 + ((sgrp ^ ((row >> 1) & 3)) << 4);
  }
#pragma unroll
  for (int fn = 0; fn < 4; ++fn) {
    int row = gn * 64 + fn * 16 + fr;
    bOff[fn] = 16384 + row * 64 + ((sgrp ^ ((row >> 1) & 3)) << 4);
  }

  auto rdf = [&](int slotB, int off) -> bf16x8 {
    return *(const bf16x8*)((const char*)lds + slotB + off);
  };

  auto decode = [&](int t, const unsigned short*& Ag, const unsigned short*& Bg,
                    int& n0v, int& miv, int& siv) {
    miv = t / 48;
    int r = t % 48;
    int ni = r & 3;
    siv = r >> 2;
    Ag = xb + (size_t)(miv * 256) * D_;
    Bg = wt + ((size_t)siv * D_ + ni * 128) * D_;
    n0v = ni * 128;
  };

  const int xcd = blockIdx.x & 7;
  const int idx = blockIdx.x >> 3;
  const int limit = (xcd + 1) * chunk;
  int ti = xcd * chunk + idx;
  if (ti >= limit || ti >= tiles) return;

  const unsigned short *Ag, *Bg, *Agn = nullptr, *Bgn = nullptr;
  int n0, mi, si, n0n, min_, sin_;
  decode(ti, Ag, Bg, n0, mi, si);
  int tin = ti + bpx;
  bool hasNext = tin < limit;
  if (hasNext) decode(tin, Agn, Bgn, n0n, min_, sin_);

  // ring-3 slot byte-bases
  int rdB = 0, stB = 2 * 24576;
  auto adv = [](int s) { return s == 2 * 24576 ? 0 : s + 24576; };

  // prologue: stage K-tiles 0,1; land 0; preload its frags
  stage(Ag, Bg, 0);
  stage(Ag + 32, Bg + 32, 24576);
  asm volatile("s_waitcnt vmcnt(6)" ::: "memory");
  __builtin_amdgcn_s_barrier();

  bf16x8 afA[4], afB[4], bfrA[4];
#pragma unroll
  for (int fm = 0; fm < 4; ++fm) afA[fm] = rdf(0, aOff[fm]);
#pragma unroll
  for (int fm = 0; fm < 4; ++fm) afB[fm] = rdf(0, aOff[4 + fm]);
#pragma unroll
  for (int fn = 0; fn < 4; ++fn) bfrA[fn] = rdf(0, bOff[fn]);

  while (true) {
    f32x4 acc[2][4][4];
#pragma unroll
    for (int ms = 0; ms < 2; ++ms)
#pragma unroll
      for (int fm = 0; fm < 4; ++fm)
#pragma unroll
        for (int fn = 0; fn < 4; ++fn)
#pragma unroll
          for (int e = 0; e < 4; ++e) acc[ms][fm][fn][e] = 0.f;

    float bv[4];
#pragma unroll
    for (int fn = 0; fn < 4; ++fn) bv[fn] = bias[n0 + gn * 64 + fn * 16 + fr];

#pragma unroll
    for (int kt = 0; kt < 16; ++kt) {
      // 1) stage K-tile kt+2 (this tile, or next tile's kt-14)
      bool st = false;
      if (kt < 14) {
        stage(Ag + (kt + 2) * 32, Bg + (kt + 2) * 32, stB);
        st = true;
      } else if (hasNext) {
        stage(Agn + (kt - 14) * 32, Bgn + (kt - 14) * 32, stB);
        st = true;
      }

      // 2) MFMA cluster ms0
      __builtin_amdgcn_s_setprio(1);
#pragma unroll
      for (int fm = 0; fm < 4; ++fm)
#pragma unroll
        for (int fn = 0; fn < 4; ++fn)
          acc[0][fm][fn] = __builtin_amdgcn_mfma_f32_16x16x32_bf16(
              afA[fm], bfrA[fn], acc[0][fm][fn], 0, 0, 0);
      __builtin_amdgcn_s_setprio(0);

      // 3) counted wait (next K-tile's 6 loads must have landed), barrier
      if (st) {
        asm volatile("s_waitcnt vmcnt(6)" ::: "memory");
      } else if (kt == 14) {
        asm volatile("s_waitcnt vmcnt(0)" ::: "memory");
      }
      __builtin_amdgcn_s_barrier();

      // 4) preload ALL next-K-tile frags (overlap with ms1 cluster below)
      const int rdN = adv(rdB);
      bf16x8 afAn[4], afBn[4], bfn[4];
      const bool pre = (kt < 15) || hasNext;
      if (pre) {
#pragma unroll
        for (int fm = 0; fm < 4; ++fm) afAn[fm] = rdf(rdN, aOff[fm]);
#pragma unroll
        for (int fn = 0; fn < 4; ++fn) bfn[fn] = rdf(rdN, bOff[fn]);
#pragma unroll
        for (int fm = 0; fm < 4; ++fm) afBn[fm] = rdf(rdN, aOff[4 + fm]);
      }

      // 5) MFMA cluster ms1
      __builtin_amdgcn_s_setprio(1);
#pragma unroll
      for (int fm = 0; fm < 4; ++fm)
#pragma unroll
        for (int fn = 0; fn < 4; ++fn)
          acc[1][fm][fn] = __builtin_amdgcn_mfma_f32_16x16x32_bf16(
              afB[fm], bfrA[fn], acc[1][fm][fn], 0, 0, 0);
      __builtin_amdgcn_s_setprio(0);

      // 6) rotate
      if (pre) {
#pragma unroll
        for (int fm = 0; fm < 4; ++fm) afA[fm] = afAn[fm];
#pragma unroll
        for (int fm = 0; fm < 4; ++fm) afB[fm] = afBn[fm];
#pragma unroll
        for (int fn = 0; fn < 4; ++fn) bfrA[fn] = bfn[fn];
      }
      rdB = rdN;
      stB = adv(stB);
    }

    // epilogue: bias + bf16 store (overlaps next tile's in-flight stages)
#pragma unroll
    for (int ms = 0; ms < 2; ++ms) {
#pragma unroll
      for (int fm = 0; fm < 4; ++fm) {
#pragma unroll
        for (int r = 0; r < 4; ++r) {
          int m = mi * 256 + gm * 128 + ms * 64 + fm * 16 + sgrp * 4 + r;
          int bl = m >> 10, t = m & 1023;
          size_t orow = (((size_t)bl * S_ + si) * T_ + t) * D_;
#pragma unroll
          for (int fn = 0; fn < 4; ++fn) {
            int o = n0 + gn * 64 + fn * 16 + fr;
            xp[orow + o] = f2bf(acc[ms][fm][fn][r] + bv[fn]);
          }
        }
      }
    }

    if (!hasNext) break;
    ti = tin;
    Ag = Agn; Bg = Bgn; n0 = n0n; mi = min_; si = sin_;
    tin = ti + bpx;
    hasNext = tin < limit;
    if (hasNext) decode(tin, Agn, Bgn, n0n, min_, sin_);
  }
}

// ---- predictions: one wave per (b, 4 x tt); 12x11 tiles via 16 MFMAs each --
__global__ __launch_bounds__(256) void pred_k(
    const unsigned short* __restrict__ xp,   // [bc][12][1024][512]
    const unsigned short* __restrict__ yT,   // [16][1024][512]
    const int* __restrict__ negs,            // [16][10][1024]
    float* __restrict__ preds, int b0) {
  const int w = threadIdx.x >> 6, l = threadIdx.x & 63;
  const int bl = blockIdx.y;
  const int b = b0 + bl;
  const int fr = l & 15;
  const int koff = (l >> 4) * 8;

  const unsigned short* arow[4];
  const unsigned short* brow[4];
  int tts[4];
#pragma unroll
  for (int q = 0; q < 4; ++q) {
    int tt = blockIdx.x * 4 + w + q * 256;
    tts[q] = tt;
    int t = tt - 1 - fr;
    bool av = (fr < S_) && (t >= 0);
    arow[q] = xp + (((size_t)bl * S_ + (av ? fr : 0)) * T_ + (av ? t : 0)) * D_;
    int j = tt;
    if (fr >= 1 && fr <= 10) j = negs[b * (10 * T_) + (fr - 1) * T_ + tt];
    brow[q] = yT + ((size_t)b * T_ + j) * D_;
  }

  f32x4 acc[4];
#pragma unroll
  for (int q = 0; q < 4; ++q)
#pragma unroll
    for (int e = 0; e < 4; ++e) acc[q][e] = 0.f;

#pragma unroll
  for (int kk = 0; kk < 16; ++kk) {
#pragma unroll
    for (int q = 0; q < 4; ++q) {
      bf16x8 a = *(const bf16x8*)(arow[q] + kk * 32 + koff);
      bf16x8 bb = *(const bf16x8*)(brow[q] + kk * 32 + koff);
      acc[q] = __builtin_amdgcn_mfma_f32_16x16x32_bf16(a, bb, acc[q], 0, 0, 0);
    }
  }

#pragma unroll
  for (int q = 0; q < 4; ++q) {
#pragma unroll
    for (int r = 0; r < 4; ++r) {
      int ii = (l >> 4) * 4 + r;
      int to = tts[q] - 1 - ii;
      if (ii < S_ && fr < C_ && tts[q] >= 1 && to >= 0) {
        int len = T_ - 1 - ii;
        preds[pred_base(ii) + ((size_t)fr * B_ + b) * len + to] = acc[q][r];
      }
    }
  }
}

extern "C" void kernel_launch(void* const* d_in, const int* in_sizes, int n_in,
                              void* d_out, int out_size, void* d_ws, size_t ws_size,
                              hipStream_t stream) {
  (void)in_sizes; (void)n_in; (void)out_size;
  const float* x = (const float*)d_in[0];
  const float* y = (const float*)d_in[1];
  const float* W = (const float*)d_in[2];
  const float* bias = (const float*)d_in[3];
  const int* negs = (const int*)d_in[4];
  float* out = (float*)d_out;
  char* ws = (char*)d_ws;

  unsigned short* wt = (unsigned short*)ws;                         // 6,291,456 B
  unsigned short* xb = (unsigned short*)(ws + 6291456);             // 16,777,216 B
  unsigned short* yT = (unsigned short*)(ws + 6291456 + 16777216);  // 16,777,216 B
  unsigned short* xp = (unsigned short*)(ws + 6291456 + 2 * 16777216);
  const size_t fixed = 6291456 + (size_t)2 * 16777216;              // 39,845,888
  const size_t xp_per_b = (size_t)S_ * T_ * D_ * 2;                 // 12,582,912
  int nb = 1;
  if (ws_size > fixed) {
    size_t cap = (ws_size - fixed) / xp_per_b;
    nb = cap < 1 ? 1 : (cap > 16 ? 16 : (int)cap);
  }

  hipLaunchKernelGGL(prep_w, dim3(16, 16), dim3(256), 0, stream, W, wt);
  hipLaunchKernelGGL(prep_t2, dim3(32, 16, 32), dim3(256), 0, stream, x, y, xb, yT);
  hipLaunchKernelGGL(labels_k, dim3((P_TOTAL + 255) / 256), dim3(256), 0, stream,
                     out + P_TOTAL);

  for (int b0 = 0; b0 < B_; b0 += nb) {
    int bc = (B_ - b0) < nb ? (B_ - b0) : nb;
    int tiles = bc * 4 * 4 * 12;              // 256m x 128n tiles
    int grid = tiles < 512 ? tiles : 512;     // both cases %8 == 0
    int chunk = tiles / 8;
    int bpx = grid / 8;
    hipLaunchKernelGGL(gemm_xp, dim3(grid), dim3(256), 0, stream,
                       xb + (size_t)b0 * T_ * D_, wt, bias, xp,
                       tiles, chunk, bpx);
    hipLaunchKernelGGL(pred_k, dim3(64, bc), dim3(256), 0, stream,
                       xp, yT, negs, out, b0);
  }
}

// Round 6
// 211.560 us; speedup vs baseline: 1.2251x; 1.2251x over previous
//
#include <hip/hip_runtime.h>

typedef __bf16 bf16x8 __attribute__((ext_vector_type(8)));
typedef float f32x4 __attribute__((ext_vector_type(4)));

#define B_ 16
#define T_ 1024
#define D_ 512
#define S_ 12
#define C_ 11
static constexpr int P_TOTAL = 2148960;  // 176 * (12*1024 - 78)

__device__ __host__ inline constexpr int pred_base(int i) {
  return C_ * B_ * (T_ * i - (i * (i + 1)) / 2);
}

__device__ inline unsigned short f2bf(float f) {
  unsigned int u = __float_as_uint(f);
  u += 0x7FFF + ((u >> 16) & 1);   // round-to-nearest-even
  return (unsigned short)(u >> 16);
}

__device__ inline void gld16(const void* g, void* l) {
  __builtin_amdgcn_global_load_lds(
      (const __attribute__((address_space(1))) void*)g,
      (__attribute__((address_space(3))) void*)l, 16, 0, 0);
}

// ---------------- prep: W [i][o][s] f32 -> wt [s][o][i] bf16 ----------------
__global__ __launch_bounds__(256) void prep_w(const float* __restrict__ W,
                                              unsigned short* __restrict__ wt) {
  __shared__ unsigned short tile[32][33][12];
  const int i0 = blockIdx.x * 32, o0 = blockIdx.y * 32;
#pragma unroll
  for (int q = 0; q < 48; ++q) {
    int idx = threadIdx.x + q * 256;
    int ii = idx / 384, rem = idx % 384;
    tile[ii][rem / 12][rem % 12] =
        f2bf(W[(size_t)(i0 + ii) * 6144 + (size_t)o0 * 12 + rem]);
  }
  __syncthreads();
#pragma unroll
  for (int q = 0; q < 48; ++q) {
    int idx = threadIdx.x + q * 256;
    int ss = idx / 1024, rem = idx % 1024;
    int oo = rem / 32, ii = rem % 32;
    wt[(size_t)ss * (D_ * D_) + (size_t)(o0 + oo) * D_ + (i0 + ii)] = tile[ii][oo][ss];
  }
}

// -- prep: transpose [b][D][T] f32 -> [b][T][D] bf16, both x and y (z=0..31) --
__global__ __launch_bounds__(256) void prep_t2(const float* __restrict__ xin,
                                               const float* __restrict__ yin,
                                               unsigned short* __restrict__ xo,
                                               unsigned short* __restrict__ yo) {
  __shared__ float tile[32][33];
  const int t0 = blockIdx.x * 32;
  const int d0 = blockIdx.y * 32;
  const int b = blockIdx.z & 15;
  const float* in = (blockIdx.z < 16) ? xin : yin;
  unsigned short* ob = (blockIdx.z < 16) ? xo : yo;
  const float* ib = in + (size_t)b * D_ * T_;
  const int r = threadIdx.x / 32, c = threadIdx.x % 32;
#pragma unroll
  for (int p = 0; p < 4; ++p) {
    int rr = r + p * 8;
    tile[rr][c] = ib[(size_t)(d0 + rr) * T_ + t0 + c];
  }
  __syncthreads();
  unsigned short* op = ob + (size_t)b * T_ * D_;
#pragma unroll
  for (int p = 0; p < 4; ++p) {
    int rr = r + p * 8;
    op[(size_t)(t0 + rr) * D_ + d0 + c] = f2bf(tile[c][rr]);
  }
}

// ---------------- labels ----------------
__global__ void labels_k(float* __restrict__ lab) {
  int k = blockIdx.x * 256 + threadIdx.x;
  if (k >= P_TOTAL) return;
  int i = 0;
#pragma unroll
  for (int q = 1; q < 12; ++q)
    if (k >= pred_base(q)) i = q;
  int rel = k - pred_base(i);
  int len = T_ - 1 - i;
  lab[k] = (rel < B_ * len) ? 1.0f : 0.0f;
}

// ---- GEMM: xp[bl][s][t][o] = xb[m][i] * wt[s][o][i] + bias[o] --------------
// m201-style 8-phase port: 256x256 tile, BK=64, 8 waves (2Mx4N), 2 LDS buffers
// (128 KiB). Per K-step: 4 quadrant-phases {ds_reads | stage 1 half-tile |
// counted vmcnt | barrier | 16 MFMA | barrier}. Wave sub-tiles are split
// non-contiguously (gm*64 + mh*128 / gn*32 + nh*128) so each phase reads only
// already-landed half-tiles; waits: vmcnt(2)@p0, vmcnt(4)@p3, never 0 mid-loop.
__global__ __launch_bounds__(512, 1) void gemm_xp(
    const unsigned short* __restrict__ xb,   // [bc*1024][512]
    const unsigned short* __restrict__ wt,   // [12][512 o][512 i]
    const float* __restrict__ bias,          // [512]
    unsigned short* __restrict__ xp,         // [bc][12][1024][512]
    int tiles, int mtiles) {
  __shared__ char ldsb[131072];  // 2 bufs x (A[256][64] 32KB + B[256][64] 32KB)
  const int tid = threadIdx.x;
  const int w = tid >> 6, l = tid & 63;
  const int gm = w >> 2, gn = w & 3;
  const int fr = l & 15, sgrp = l >> 4;

  // ---- staging constants (linear LDS dest, inverse-swizzled global src) ----
  const int dox0 = tid * 16, dox1 = tid * 16 + 8192;
  const int rl0 = dox0 >> 7, rl1 = dox1 >> 7;         // local rows 0..127
  const int col = dox0 & 127;
  const int sco0 = rl0 * 1024 + (col ^ ((rl0 & 7) << 4));
  const int sco1 = rl1 * 1024 + (col ^ ((rl1 & 7) << 4));

  // stage one 16KB half-tile: panel = byte ptr to 256x512-short operand panel
  auto stageH = [&](const char* panel, int ks, int half, int ldsBase) {
    const char* s = panel + half * 131072 + ks * 128;
    char* d = ldsb + ldsBase + half * 16384;
    gld16(s + sco0, d + dox0);
    gld16(s + sco1, d + dox1);
  };

  // ---- fragment read constants ----
  const int sw = (fr & 7) << 4;
  const int colk0 = (sgrp * 16) ^ sw;        // kk=0
  const int colk1 = (64 + sgrp * 16) ^ sw;   // kk=1
  const int aRowB = (gm * 64 + fr) * 128;    // byte row base in A tile
  const int bRowB = 32768 + (gn * 32 + fr) * 128;

  auto ldf = [&](int off) -> bf16x8 {
    return *(const bf16x8*)(ldsb + off);
  };

  auto decode = [&](int t, const unsigned short*& Ag, const unsigned short*& Bg,
                    int& n0v, int& miv, int& siv) {
    miv = t % mtiles;
    int rest = t / mtiles;
    int ni = rest & 1;
    siv = rest >> 1;
    Ag = xb + (size_t)(miv * 256) * D_;
    Bg = wt + ((size_t)siv * D_ + ni * 256) * D_;
    n0v = ni * 256;
  };

  int ti = blockIdx.x;
  if (ti >= tiles) return;
  const unsigned short *Ag, *Bg, *Agn = nullptr, *Bgn = nullptr;
  int n0, mi, si, n0n, min_, sin_;
  decode(ti, Ag, Bg, n0, mi, si);
  int tin = ti + gridDim.x;
  bool hasNext = tin < tiles;
  if (hasNext) decode(tin, Agn, Bgn, n0n, min_, sin_);

#define BAR()  asm volatile("" ::: "memory"); __builtin_amdgcn_s_barrier(); \
               asm volatile("" ::: "memory")

  // prologue: all 4 halves of K-step 0 into buf0 (order AH0,BH0,AH1,BH1)
  stageH((const char*)Ag, 0, 0, 0);
  stageH((const char*)Bg, 0, 0, 32768);
  stageH((const char*)Ag, 0, 1, 0);
  stageH((const char*)Bg, 0, 1, 32768);
  asm volatile("s_waitcnt vmcnt(4)" ::: "memory");
  BAR();

  while (true) {
    f32x4 acc[8][4];   // [mh*4+fm][nh*2+fn]
#pragma unroll
    for (int a = 0; a < 8; ++a)
#pragma unroll
      for (int bq = 0; bq < 4; ++bq)
#pragma unroll
        for (int e = 0; e < 4; ++e) acc[a][bq][e] = 0.f;

    float bv[2][2];
#pragma unroll
    for (int nh = 0; nh < 2; ++nh)
#pragma unroll
      for (int fn = 0; fn < 2; ++fn)
        bv[nh][fn] = bias[n0 + gn * 32 + nh * 128 + fn * 16 + fr];

#pragma unroll
    for (int ks = 0; ks < 8; ++ks) {
      const int bufB = (ks & 1) * 65536;
      const int nbufB = bufB ^ 65536;
      const bool st = (ks < 7) || hasNext;
      const char* pA = (ks < 7) ? (const char*)Ag : (const char*)Agn;
      const char* pB = (ks < 7) ? (const char*)Bg : (const char*)Bgn;
      const int kn = (ks < 7) ? ks + 1 : 0;
      bf16x8 af[2][4], b0[2][2], b1[2][2];

      // ================= phase 0 : q(mh0, nh0) =================
#pragma unroll
      for (int fm = 0; fm < 4; ++fm) {
        af[0][fm] = ldf(bufB + aRowB + fm * 2048 + colk0);
        af[1][fm] = ldf(bufB + aRowB + fm * 2048 + colk1);
      }
#pragma unroll
      for (int fn = 0; fn < 2; ++fn) {
        b0[0][fn] = ldf(bufB + bRowB + fn * 2048 + colk0);
        b0[1][fn] = ldf(bufB + bRowB + fn * 2048 + colk1);
      }
      if (st) {
        stageH(pA, kn, 0, nbufB);
        asm volatile("s_waitcnt vmcnt(2)" ::: "memory");
      } else {
        asm volatile("s_waitcnt vmcnt(0)" ::: "memory");
      }
      BAR();
      __builtin_amdgcn_s_setprio(1);
#pragma unroll
      for (int kk = 0; kk < 2; ++kk)
#pragma unroll
        for (int fm = 0; fm < 4; ++fm)
#pragma unroll
          for (int fn = 0; fn < 2; ++fn)
            acc[fm][fn] = __builtin_amdgcn_mfma_f32_16x16x32_bf16(
                af[kk][fm], b0[kk][fn], acc[fm][fn], 0, 0, 0);
      __builtin_amdgcn_s_setprio(0);
      BAR();

      // ================= phase 1 : q(mh0, nh1) =================
#pragma unroll
      for (int fn = 0; fn < 2; ++fn) {
        b1[0][fn] = ldf(bufB + bRowB + 16384 + fn * 2048 + colk0);
        b1[1][fn] = ldf(bufB + bRowB + 16384 + fn * 2048 + colk1);
      }
      if (st) stageH(pB, kn, 0, nbufB + 32768);
      BAR();
      __builtin_amdgcn_s_setprio(1);
#pragma unroll
      for (int kk = 0; kk < 2; ++kk)
#pragma unroll
        for (int fm = 0; fm < 4; ++fm)
#pragma unroll
          for (int fn = 0; fn < 2; ++fn)
            acc[fm][2 + fn] = __builtin_amdgcn_mfma_f32_16x16x32_bf16(
                af[kk][fm], b1[kk][fn], acc[fm][2 + fn], 0, 0, 0);
      __builtin_amdgcn_s_setprio(0);
      BAR();

      // ================= phase 2 : q(mh1, nh1) =================
#pragma unroll
      for (int fm = 0; fm < 4; ++fm) {
        af[0][fm] = ldf(bufB + aRowB + 16384 + fm * 2048 + colk0);
        af[1][fm] = ldf(bufB + aRowB + 16384 + fm * 2048 + colk1);
      }
      if (st) stageH(pA, kn, 1, nbufB);
      BAR();
      __builtin_amdgcn_s_setprio(1);
#pragma unroll
      for (int kk = 0; kk < 2; ++kk)
#pragma unroll
        for (int fm = 0; fm < 4; ++fm)
#pragma unroll
          for (int fn = 0; fn < 2; ++fn)
            acc[4 + fm][2 + fn] = __builtin_amdgcn_mfma_f32_16x16x32_bf16(
                af[kk][fm], b1[kk][fn], acc[4 + fm][2 + fn], 0, 0, 0);
      __builtin_amdgcn_s_setprio(0);
      BAR();

      // ================= phase 3 : q(mh1, nh0) =================
      if (st) stageH(pB, kn, 1, nbufB + 32768);
      BAR();
      __builtin_amdgcn_s_setprio(1);
#pragma unroll
      for (int kk = 0; kk < 2; ++kk)
#pragma unroll
        for (int fm = 0; fm < 4; ++fm)
#pragma unroll
          for (int fn = 0; fn < 2; ++fn)
            acc[4 + fm][fn] = __builtin_amdgcn_mfma_f32_16x16x32_bf16(
                af[kk][fm], b0[kk][fn], acc[4 + fm][fn], 0, 0, 0);
      __builtin_amdgcn_s_setprio(0);
      if (st) asm volatile("s_waitcnt vmcnt(4)" ::: "memory");
      BAR();
    }

    // epilogue: bias + bf16 store (staging for next tile rides through)
#pragma unroll
    for (int mh = 0; mh < 2; ++mh) {
#pragma unroll
      for (int fm = 0; fm < 4; ++fm) {
#pragma unroll
        for (int r = 0; r < 4; ++r) {
          int m = mi * 256 + gm * 64 + mh * 128 + fm * 16 + sgrp * 4 + r;
          int bl = m >> 10, t = m & 1023;
          size_t orow = (((size_t)bl * S_ + si) * T_ + t) * D_;
#pragma unroll
          for (int nh = 0; nh < 2; ++nh)
#pragma unroll
            for (int fn = 0; fn < 2; ++fn) {
              int o = n0 + gn * 32 + nh * 128 + fn * 16 + fr;
              xp[orow + o] = f2bf(acc[mh * 4 + fm][nh * 2 + fn][r] + bv[nh][fn]);
            }
        }
      }
    }

    if (!hasNext) break;
    ti = tin;
    Ag = Agn; Bg = Bgn; n0 = n0n; mi = min_; si = sin_;
    tin = ti + gridDim.x;
    hasNext = tin < tiles;
    if (hasNext) decode(tin, Agn, Bgn, n0n, min_, sin_);
  }
#undef BAR
}

// ---- predictions: one wave per (b, 4 x tt); 12x11 tiles via 16 MFMAs each --
__global__ __launch_bounds__(256) void pred_k(
    const unsigned short* __restrict__ xp,   // [bc][12][1024][512]
    const unsigned short* __restrict__ yT,   // [16][1024][512]
    const int* __restrict__ negs,            // [16][10][1024]
    float* __restrict__ preds, int b0) {
  const int w = threadIdx.x >> 6, l = threadIdx.x & 63;
  const int bl = blockIdx.y;
  const int b = b0 + bl;
  const int fr = l & 15;
  const int koff = (l >> 4) * 8;

  const unsigned short* arow[4];
  const unsigned short* brow[4];
  int tts[4];
#pragma unroll
  for (int q = 0; q < 4; ++q) {
    int tt = blockIdx.x * 4 + w + q * 256;
    tts[q] = tt;
    int t = tt - 1 - fr;
    bool av = (fr < S_) && (t >= 0);
    arow[q] = xp + (((size_t)bl * S_ + (av ? fr : 0)) * T_ + (av ? t : 0)) * D_;
    int j = tt;
    if (fr >= 1 && fr <= 10) j = negs[b * (10 * T_) + (fr - 1) * T_ + tt];
    brow[q] = yT + ((size_t)b * T_ + j) * D_;
  }

  f32x4 acc[4];
#pragma unroll
  for (int q = 0; q < 4; ++q)
#pragma unroll
    for (int e = 0; e < 4; ++e) acc[q][e] = 0.f;

#pragma unroll
  for (int kk = 0; kk < 16; ++kk) {
#pragma unroll
    for (int q = 0; q < 4; ++q) {
      bf16x8 a = *(const bf16x8*)(arow[q] + kk * 32 + koff);
      bf16x8 bb = *(const bf16x8*)(brow[q] + kk * 32 + koff);
      acc[q] = __builtin_amdgcn_mfma_f32_16x16x32_bf16(a, bb, acc[q], 0, 0, 0);
    }
  }

#pragma unroll
  for (int q = 0; q < 4; ++q) {
#pragma unroll
    for (int r = 0; r < 4; ++r) {
      int ii = (l >> 4) * 4 + r;
      int to = tts[q] - 1 - ii;
      if (ii < S_ && fr < C_ && tts[q] >= 1 && to >= 0) {
        int len = T_ - 1 - ii;
        preds[pred_base(ii) + ((size_t)fr * B_ + b) * len + to] = acc[q][r];
      }
    }
  }
}

extern "C" void kernel_launch(void* const* d_in, const int* in_sizes, int n_in,
                              void* d_out, int out_size, void* d_ws, size_t ws_size,
                              hipStream_t stream) {
  (void)in_sizes; (void)n_in; (void)out_size;
  const float* x = (const float*)d_in[0];
  const float* y = (const float*)d_in[1];
  const float* W = (const float*)d_in[2];
  const float* bias = (const float*)d_in[3];
  const int* negs = (const int*)d_in[4];
  float* out = (float*)d_out;
  char* ws = (char*)d_ws;

  unsigned short* wt = (unsigned short*)ws;                         // 6,291,456 B
  unsigned short* xb = (unsigned short*)(ws + 6291456);             // 16,777,216 B
  unsigned short* yT = (unsigned short*)(ws + 6291456 + 16777216);  // 16,777,216 B
  unsigned short* xp = (unsigned short*)(ws + 6291456 + 2 * 16777216);
  const size_t fixed = 6291456 + (size_t)2 * 16777216;              // 39,845,888
  const size_t xp_per_b = (size_t)S_ * T_ * D_ * 2;                 // 12,582,912
  int nb = 1;
  if (ws_size > fixed) {
    size_t cap = (ws_size - fixed) / xp_per_b;
    nb = cap < 1 ? 1 : (cap > 16 ? 16 : (int)cap);
  }

  hipLaunchKernelGGL(prep_w, dim3(16, 16), dim3(256), 0, stream, W, wt);
  hipLaunchKernelGGL(prep_t2, dim3(32, 16, 32), dim3(256), 0, stream, x, y, xb, yT);
  hipLaunchKernelGGL(labels_k, dim3((P_TOTAL + 255) / 256), dim3(256), 0, stream,
                     out + P_TOTAL);

  for (int b0 = 0; b0 < B_; b0 += nb) {
    int bc = (B_ - b0) < nb ? (B_ - b0) : nb;
    int tiles = bc * 4 * 2 * 12;              // 256x256 tiles
    int grid = tiles < 256 ? tiles : 256;
    hipLaunchKernelGGL(gemm_xp, dim3(grid), dim3(512), 0, stream,
                       xb + (size_t)b0 * T_ * D_, wt, bias, xp,
                       tiles, bc * 4);
    hipLaunchKernelGGL(pred_k, dim3(64, bc), dim3(256), 0, stream,
                       xp, yT, negs, out, b0);
  }
}